// Round 2
// baseline (389.921 us; speedup 1.0000x reference)
//
#include <hip/hip_runtime.h>
#include <stdint.h>

// ---------------------------------------------------------------------------
// OptitationLayer: sliding-window attention (W=9) with projections.
//   S=32768, D=1024, R=256. Inputs/outputs FLOAT32; bf16 MFMA internally.
// Pipeline (5 kernels):
//   prep_w : coalesced LDS-tile transposes f32->bf16: Wt[768][1024], Wot[1024][256]
//   cvt_x  : x f32 -> bf16 (BW-bound pass)
//   gemm8  : QKV[S][768] bf16 = x_bf16 @ W + bias   (256^2 tile, counted-vmcnt)
//   attn   : QKV[i][0:256] <- softmax-window ctx (in-place, 4 queries/wave)
//   gemm8  : out[S][1024] f32 = ctx @ Wo + bo
//
// gemm8 schedule (8-phase-class, T2+T3+T4+T5 from the technique catalog):
//   BM=BN=256, BK=32, 512 threads (8 waves, 2M x 4N), ring of 3 K-tile LDS
//   buffers (96 KB). Per K-tile: 2 phases x 16 MFMA. While computing tile t,
//   stage tile t+2 (A in ph1, B in ph2) via global_load_lds. ONE counted
//   s_waitcnt vmcnt(4) per K-tile (never 0 in steady state) keeps 2 K-tiles
//   of loads in flight across raw s_barriers. Race safety: writer of a
//   buffer issues only after the barrier following its last reader's
//   lgkm-drained MFMA; readers gated by all-waves vmcnt+barrier.
//   LDS swizzle: 16B chunk c of row r stored at c ^ ((r>>1)&3)  -> 2-way
//   bank aliasing (free); global source pre-inverse-swizzled (rule 21).
// ---------------------------------------------------------------------------

typedef __attribute__((ext_vector_type(8))) short short8;   // 8 x bf16 frag
typedef __attribute__((ext_vector_type(4))) float floatx4;  // MFMA acc

typedef __attribute__((address_space(1))) const void global_cv;
typedef __attribute__((address_space(3))) void lds_v;

__device__ __forceinline__ float b2f(unsigned short u) {
  union { float f; uint32_t i; } v; v.i = ((uint32_t)u) << 16; return v.f;
}
__device__ __forceinline__ unsigned short f2b(float f) {
  union { float f; uint32_t i; } v; v.f = f;
  uint32_t x = v.i;
  return (unsigned short)((x + 0x7FFFu + ((x >> 16) & 1u)) >> 16);
}
// pack two f32 -> two bf16 (round half-up; 3 VALU ops)
__device__ __forceinline__ uint32_t pack2bf(float a, float b) {
  uint32_t ua = (__float_as_uint(a) + 0x8000u) >> 16;
  uint32_t ub = (__float_as_uint(b) + 0x8000u) & 0xFFFF0000u;
  return ua | ub;
}

// async 16B global->LDS; lane i lands at lds_base + i*16 (wave-uniform base)
__device__ __forceinline__ void async16(const unsigned short* g, unsigned short* s) {
  __builtin_amdgcn_global_load_lds((global_cv*)g, (lds_v*)s, 16, 0, 0);
}

__device__ __forceinline__ void storeC(unsigned short* C, size_t idx, float v) {
  C[idx] = f2b(v);
}
__device__ __forceinline__ void storeC(float* C, size_t idx, float v) {
  C[idx] = v;
}

// x (f32, n8*8 elems) -> xb (bf16). Pure-BW grid-stride pass.
__global__ __launch_bounds__(256) void cvt_x(
    const float* __restrict__ x, unsigned short* __restrict__ xb, int n8)
{
  const int stride = gridDim.x * blockDim.x;
  for (int i = blockIdx.x * blockDim.x + threadIdx.x; i < n8; i += stride) {
    const float4 u = ((const float4*)x)[2 * i];
    const float4 v = ((const float4*)x)[2 * i + 1];
    uint4 pk;
    pk.x = pack2bf(u.x, u.y); pk.y = pack2bf(u.z, u.w);
    pk.z = pack2bf(v.x, v.y); pk.w = pack2bf(v.z, v.w);
    ((uint4*)xb)[i] = pk;
  }
}

// ---------------------------------------------------------------------------
// gemm8: C[m][n] = sum_k A[m][k]*Bt[n][k] + bias[n].  A,Bt bf16.
// 256x256 tile, BK=32, ring-3 LDS, counted vmcnt. NTB = N/256 (compile-time).
// Grid: (M/256)*NTB blocks of 512 threads; bijective XCD swizzle.
// ---------------------------------------------------------------------------
template <typename CT, int NTB>
__global__ __launch_bounds__(512, 2) void gemm8(
    const unsigned short* __restrict__ A,
    const unsigned short* __restrict__ Bt,
    const float* __restrict__ bias,
    CT* __restrict__ C,
    int K, int lda, int ldb, int ldc)
{
  __shared__ __align__(16) unsigned short sA[3][256 * 32];  // 48 KB
  __shared__ __align__(16) unsigned short sB[3][256 * 32];  // 48 KB

  const int tid = threadIdx.x;
  const int w   = tid >> 6;        // wave 0..7
  const int l   = tid & 63;
  const int l15 = l & 15;
  const int q   = l >> 4;

  const int wm  = (w >> 2) * 128;  // wave row base: 0 / 128
  const int wn  = (w & 3) * 64;    // wave col base: 0..192

  // XCD-aware remap: all n-tiles of an m-row on one XCD
  const int bt  = blockIdx.x;
  const int xcd = bt & 7;
  const int j_  = bt >> 3;
  const int n0  = (j_ % NTB) * 256;
  const int m0  = ((j_ / NTB) * 8 + xcd) * 256;

  // ---- staging geometry: per issue, wave covers 16 rows x 4 chunks (16B)
  const int sr  = l >> 2;                  // row within 16-row group
  const int pcs = l & 3;                   // physical chunk
  const int lc  = pcs ^ ((sr >> 1) & 3);   // logical chunk (inverse swizzle)
  const unsigned short* Ap[2];
  const unsigned short* Bp[2];
  #pragma unroll
  for (int j = 0; j < 2; ++j) {
    const int rr = j * 128 + w * 16 + sr;
    Ap[j] = A  + (size_t)(m0 + rr) * lda + lc * 8;
    Bp[j] = Bt + (size_t)(n0 + rr) * ldb + lc * 8;
  }

  floatx4 acc[8][4];
  #pragma unroll
  for (int i = 0; i < 8; ++i)
    #pragma unroll
    for (int j = 0; j < 4; ++j)
      #pragma unroll
      for (int t = 0; t < 4; ++t) acc[i][j][t] = 0.f;

  // fragment read offsets (shorts): row*32 + swizzled-chunk*8
  const int fpc  = (q ^ ((l15 >> 1) & 3)) * 8;
  const int arow = (wm + l15) * 32 + fpc;
  const int brow = (wn + l15) * 32 + fpc;

  const int NT = K >> 5;   // K-tiles of 32

  // ---- prologue: stage tiles 0 and 1
  #pragma unroll
  for (int j = 0; j < 2; ++j) async16(Ap[j],      sA[0] + (j * 128 + w * 16) * 32);
  #pragma unroll
  for (int j = 0; j < 2; ++j) async16(Bp[j],      sB[0] + (j * 128 + w * 16) * 32);
  #pragma unroll
  for (int j = 0; j < 2; ++j) async16(Ap[j] + 32, sA[1] + (j * 128 + w * 16) * 32);
  #pragma unroll
  for (int j = 0; j < 2; ++j) async16(Bp[j] + 32, sB[1] + (j * 128 + w * 16) * 32);
  asm volatile("s_waitcnt vmcnt(4)" ::: "memory");  // tile 0 landed
  __builtin_amdgcn_s_barrier();

  int bc = 0, bs = 2, k2 = 64;
  for (int t = 0; t < NT; ++t) {
    // ================= phase 1: quadrant mt 0..3 =================
    short8 bf[4], af[4];
    #pragma unroll
    for (int nt = 0; nt < 4; ++nt)
      bf[nt] = *(const short8*)(sB[bc] + brow + nt * 512);
    #pragma unroll
    for (int mt = 0; mt < 4; ++mt)
      af[mt] = *(const short8*)(sA[bc] + arow + mt * 512);
    if (k2 < K) {  // stage A of tile t+2 (buffer free since end of tile t-1)
      #pragma unroll
      for (int j = 0; j < 2; ++j)
        async16(Ap[j] + k2, sA[bs] + (j * 128 + w * 16) * 32);
    }
    __builtin_amdgcn_s_barrier();
    __builtin_amdgcn_s_setprio(1);
    #pragma unroll
    for (int mt = 0; mt < 4; ++mt)
      #pragma unroll
      for (int nt = 0; nt < 4; ++nt)
        acc[mt][nt] = __builtin_amdgcn_mfma_f32_16x16x32_bf16(
            af[mt], bf[nt], acc[mt][nt], 0, 0, 0);
    __builtin_amdgcn_s_setprio(0);
    __builtin_amdgcn_s_barrier();

    // ================= phase 2: quadrant mt 4..7 =================
    #pragma unroll
    for (int mt = 0; mt < 4; ++mt)
      af[mt] = *(const short8*)(sA[bc] + arow + (mt + 4) * 512);
    if (k2 < K) {  // stage B of tile t+2
      #pragma unroll
      for (int j = 0; j < 2; ++j)
        async16(Bp[j] + k2, sB[bs] + (j * 128 + w * 16) * 32);
      // publish tile t+1 (issued during t-1): allow only our own 4 loads
      asm volatile("s_waitcnt vmcnt(4)" ::: "memory");
    } else {
      asm volatile("s_waitcnt vmcnt(0)" ::: "memory");  // tail drain
    }
    __builtin_amdgcn_s_barrier();
    __builtin_amdgcn_s_setprio(1);
    #pragma unroll
    for (int mt = 0; mt < 4; ++mt)
      #pragma unroll
      for (int nt = 0; nt < 4; ++nt)
        acc[4 + mt][nt] = __builtin_amdgcn_mfma_f32_16x16x32_bf16(
            af[mt], bf[nt], acc[4 + mt][nt], 0, 0, 0);
    __builtin_amdgcn_s_setprio(0);
    __builtin_amdgcn_s_barrier();

    bc = (bc == 2) ? 0 : bc + 1;
    bs = (bs == 2) ? 0 : bs + 1;
    k2 += 32;
  }

  // ---- epilogue: C/D layout col=lane&15, row=quad*4+reg
  #pragma unroll
  for (int nt = 0; nt < 4; ++nt) {
    const int col = n0 + wn + nt * 16 + l15;
    const float bsv = bias[col];
    #pragma unroll
    for (int mt = 0; mt < 8; ++mt) {
      const int rbase = m0 + wm + mt * 16 + q * 4;
      #pragma unroll
      for (int r = 0; r < 4; ++r)
        storeC(C, (size_t)(rbase + r) * ldc + col, acc[mt][nt][r] + bsv);
    }
  }
}

// 4 queries per wave, 16 lanes per query (lane p owns dims p*16..p*16+15).
// QKV row: [Q(0..255) | K(256..511) | V(512..767)], bf16. ctx overwrites Q
// slot in place (each group reads only its own Q row, before its store).
__global__ __launch_bounds__(256) void attn_win(unsigned short* QKV)
{
  const int l   = threadIdx.x & 63;
  const int grp = l >> 4;
  const int p   = l & 15;
  const int i   = blockIdx.x * 16 + (threadIdx.x >> 6) * 4 + grp;

  unsigned short* qrow = QKV + (size_t)i * 768 + p * 16;
  float qf[16];
  {
    const short8 v0 = *(const short8*)(qrow);
    const short8 v1 = *(const short8*)(qrow + 8);
    #pragma unroll
    for (int t = 0; t < 8; ++t) {
      qf[t]     = b2f((unsigned short)v0[t]);
      qf[8 + t] = b2f((unsigned short)v1[t]);
    }
  }

  float sc[9];
  #pragma unroll
  for (int wd = 0; wd < 9; ++wd) {
    const int j = i - 8 + wd;
    if (j >= 0) {
      const unsigned short* krow = QKV + (size_t)j * 768 + 256 + p * 16;
      const short8 v0 = *(const short8*)(krow);
      const short8 v1 = *(const short8*)(krow + 8);
      float d = 0.f;
      #pragma unroll
      for (int t = 0; t < 8; ++t) {
        d += qf[t]     * b2f((unsigned short)v0[t]);
        d += qf[8 + t] * b2f((unsigned short)v1[t]);
      }
      d += __shfl_xor(d, 8, 64);
      d += __shfl_xor(d, 4, 64);
      d += __shfl_xor(d, 2, 64);
      d += __shfl_xor(d, 1, 64);
      sc[wd] = d * 0.0625f;  // 1/sqrt(256)
    } else {
      sc[wd] = -1e30f;  // finite sentinel
    }
  }

  float mx = sc[0];
  #pragma unroll
  for (int wd = 1; wd < 9; ++wd) mx = fmaxf(mx, sc[wd]);
  float e[9], s = 0.f;
  #pragma unroll
  for (int wd = 0; wd < 9; ++wd) { e[wd] = __expf(sc[wd] - mx); s += e[wd]; }
  const float inv = 1.0f / s;

  float acc[16];
  #pragma unroll
  for (int t = 0; t < 16; ++t) acc[t] = 0.f;
  #pragma unroll
  for (int wd = 0; wd < 9; ++wd) {
    const int j = i - 8 + wd;
    if (j >= 0) {
      const unsigned short* vrow = QKV + (size_t)j * 768 + 512 + p * 16;
      const short8 v0 = *(const short8*)(vrow);
      const short8 v1 = *(const short8*)(vrow + 8);
      #pragma unroll
      for (int t = 0; t < 8; ++t) {
        acc[t]     += e[wd] * b2f((unsigned short)v0[t]);
        acc[8 + t] += e[wd] * b2f((unsigned short)v1[t]);
      }
    }
  }
  short8 o0, o1;
  #pragma unroll
  for (int t = 0; t < 8; ++t) {
    o0[t] = (short)f2b(acc[t] * inv);
    o1[t] = (short)f2b(acc[8 + t] * inv);
  }
  *(short8*)(qrow)     = o0;
  *(short8*)(qrow + 8) = o1;
}

// Coalesced weight transposes via 32x32 LDS tiles (f32 -> bf16) + biases.
__global__ __launch_bounds__(256) void prep_w(
    const float* __restrict__ Wq, const float* __restrict__ Wk,
    const float* __restrict__ Wv, const float* __restrict__ Wo,
    const float* __restrict__ bq, const float* __restrict__ bk,
    const float* __restrict__ bv, const float* __restrict__ bo,
    unsigned short* __restrict__ Wt,   // [768][1024] bf16
    unsigned short* __restrict__ Wot,  // [1024][256] bf16
    float* __restrict__ bias1,         // [768] f32
    float* __restrict__ bias2)         // [1024] f32
{
  const int tt = blockIdx.x;
  if (tt < 1024) {
    __shared__ float tile[32][33];
    const float* src; unsigned short* dst; int N, Kd, k0, n0;
    if (tt < 768) {
      const int s = tt >> 8;          // 0:Wq 1:Wk 2:Wv
      const int r = tt & 255;
      src = (s == 0) ? Wq : (s == 1) ? Wk : Wv;
      N = 256; Kd = 1024;
      k0 = (r & 31) * 32;
      n0 = (r >> 5) * 32;
      dst = Wt + (size_t)s * 256 * 1024;
    } else {
      const int r = tt - 768;
      src = Wo; N = 1024; Kd = 256;
      k0 = (r & 7) * 32;
      n0 = (r >> 3) * 32;
      dst = Wot;
    }
    const int t  = threadIdx.x;
    const int rr = t >> 3;
    const int c4 = (t & 7) * 4;
    const float4 v = *(const float4*)(src + (size_t)(k0 + rr) * N + n0 + c4);
    tile[rr][c4 + 0] = v.x; tile[rr][c4 + 1] = v.y;
    tile[rr][c4 + 2] = v.z; tile[rr][c4 + 3] = v.w;
    __syncthreads();
    ushort4 o;
    o.x = f2b(tile[c4 + 0][rr]); o.y = f2b(tile[c4 + 1][rr]);
    o.z = f2b(tile[c4 + 2][rr]); o.w = f2b(tile[c4 + 3][rr]);
    *(ushort4*)(dst + (size_t)(n0 + rr) * Kd + k0 + c4) = o;
  } else {
    for (int c = threadIdx.x; c < 1792; c += 256) {
      if (c < 768)
        bias1[c] = (c < 256) ? bq[c] : (c < 512) ? bk[c - 256] : bv[c - 512];
      else
        bias2[c - 768] = bo[c - 768];
    }
  }
}

extern "C" void kernel_launch(void* const* d_in, const int* in_sizes, int n_in,
                              void* d_out, int out_size, void* d_ws, size_t ws_size,
                              hipStream_t stream) {
  const float* x  = (const float*)d_in[0];
  const float* Wq = (const float*)d_in[1];
  const float* Wk = (const float*)d_in[2];
  const float* Wv = (const float*)d_in[3];
  const float* Wo = (const float*)d_in[4];
  const float* bq = (const float*)d_in[5];
  const float* bk = (const float*)d_in[6];
  const float* bv = (const float*)d_in[7];
  const float* bo = (const float*)d_in[8];
  float* out = (float*)d_out;

  // workspace layout — xb spills into d_out if ws is small
  // (d_out = 134 MB, only consumed by the last GEMM => stream-ordered safe).
  unsigned short* ws    = (unsigned short*)d_ws;
  unsigned short* Wt    = ws;                        //   786432 bf16
  unsigned short* Wot   = Wt  + 786432;              //   262144 bf16
  float*          bias1 = (float*)(Wot + 262144);    //      768 f32
  float*          bias2 = bias1 + 768;               //     1024 f32
  unsigned short* QKV   = (unsigned short*)(bias2 + 1024);  // 25165824 bf16
  unsigned short* xb;                                // 33554432 bf16
  const size_t need = 119544832;                     // bytes incl. xb
  if (ws_size >= need) xb = QKV + 25165824;
  else                 xb = (unsigned short*)d_out;  // scratch until last GEMM

  prep_w<<<1025, 256, 0, stream>>>(Wq, Wk, Wv, Wo, bq, bk, bv, bo,
                                   Wt, Wot, bias1, bias2);

  // x f32 -> bf16
  cvt_x<<<2048, 256, 0, stream>>>(x, xb, 32768 * 1024 / 8);

  // QKV = x @ [Wq|Wk|Wv] + bias   (M=32768, N=768, K=1024)
  gemm8<unsigned short, 3><<<384, 512, 0, stream>>>(
      xb, Wt, bias1, QKV, 1024, 1024, 1024, 768);

  // windowed attention: ctx overwrites the Q slot of QKV
  attn_win<<<2048, 256, 0, stream>>>(QKV);

  // out = ctx @ Wo + bo   (M=32768, N=1024, K=256; A = QKV with lda=768)
  gemm8<float, 4><<<512, 512, 0, stream>>>(
      QKV, Wot, bias2, out, 256, 768, 256, 1024);
}

// Round 3
// 364.229 us; speedup vs baseline: 1.0705x; 1.0705x over previous
//
#include <hip/hip_runtime.h>
#include <stdint.h>

// ---------------------------------------------------------------------------
// OptitationLayer: sliding-window attention (W=9) with projections.
//   S=32768, D=1024, R=256. Inputs/outputs FLOAT32; bf16 MFMA internally.
// Pipeline (5 kernels):
//   prep_w : coalesced LDS-tile transposes f32->bf16: Wt[768][1024], Wot[1024][256]
//   cvt_x  : x f32 -> bf16 (BW-bound pass)
//   gemm_bt: QKV[S][768] bf16 = x_bf16 @ W + bias
//   attn   : QKV[i][0:256] <- softmax-window ctx (in-place, 4 queries/wave)
//   gemm_bt: out[S][1024] f32 = ctx @ Wo + bo
//
// gemm_bt schedule (T4 counted-vmcnt, multi-block occupancy):
//   128x128 tile, 4 waves, BK=32, ring-of-3 LDS K-tile buffers (48 KB ->
//   3 blocks/CU = 12 waves/CU). Per K-tile t: stage tile t+2 (4 async16/wave),
//   8 ds_read_b128, 16 MFMA, ONE s_waitcnt vmcnt(4) (drains tile t+1, keeps
//   t+2 in flight -- never 0 in steady state), ONE raw s_barrier. Loads get
//   ~2 tiles of compute in flight; 3 blocks/CU gives TLP on top.
//   Race safety: buf[(t+2)%3]'s last readers (tile t-1 ds_reads) completed
//   before the end-of-(t-1) barrier; readers of buf[t%3] gated by previous
//   tile's vmcnt(4)+barrier which drains exactly tile t's 4 loads.
//   LDS swizzle: 16B chunk c of row r at c ^ ((r>>1)&3); global source
//   pre-inverse-swizzled (both-sides rule); measured 0 bank conflicts.
// ---------------------------------------------------------------------------

typedef __attribute__((ext_vector_type(8))) short short8;   // 8 x bf16 frag
typedef __attribute__((ext_vector_type(4))) float floatx4;  // MFMA acc

typedef __attribute__((address_space(1))) const void global_cv;
typedef __attribute__((address_space(3))) void lds_v;

__device__ __forceinline__ float b2f(unsigned short u) {
  union { float f; uint32_t i; } v; v.i = ((uint32_t)u) << 16; return v.f;
}
__device__ __forceinline__ unsigned short f2b(float f) {
  union { float f; uint32_t i; } v; v.f = f;
  uint32_t x = v.i;
  return (unsigned short)((x + 0x7FFFu + ((x >> 16) & 1u)) >> 16);
}
// pack two f32 -> two bf16 (round half-up; 3 VALU ops)
__device__ __forceinline__ uint32_t pack2bf(float a, float b) {
  uint32_t ua = (__float_as_uint(a) + 0x8000u) >> 16;
  uint32_t ub = (__float_as_uint(b) + 0x8000u) & 0xFFFF0000u;
  return ua | ub;
}

// async 16B global->LDS; lane i lands at lds_base + i*16 (wave-uniform base)
__device__ __forceinline__ void async16(const unsigned short* g, unsigned short* s) {
  __builtin_amdgcn_global_load_lds((global_cv*)g, (lds_v*)s, 16, 0, 0);
}

__device__ __forceinline__ void storeC(unsigned short* C, size_t idx, float v) {
  C[idx] = f2b(v);
}
__device__ __forceinline__ void storeC(float* C, size_t idx, float v) {
  C[idx] = v;
}

// x (f32, n8*8 elems) -> xb (bf16). Pure-BW grid-stride pass.
__global__ __launch_bounds__(256) void cvt_x(
    const float* __restrict__ x, unsigned short* __restrict__ xb, int n8)
{
  const int stride = gridDim.x * blockDim.x;
  for (int i = blockIdx.x * blockDim.x + threadIdx.x; i < n8; i += stride) {
    const float4 u = ((const float4*)x)[2 * i];
    const float4 v = ((const float4*)x)[2 * i + 1];
    uint4 pk;
    pk.x = pack2bf(u.x, u.y); pk.y = pack2bf(u.z, u.w);
    pk.z = pack2bf(v.x, v.y); pk.w = pack2bf(v.z, v.w);
    ((uint4*)xb)[i] = pk;
  }
}

// ---------------------------------------------------------------------------
// gemm_bt: C[m][n] = sum_k A[m][k]*Bt[n][k] + bias[n].  A,Bt bf16.
// 128x128 tile, BK=32, ring-3 LDS, counted vmcnt. NTB = N/128 (compile-time).
// Grid: (M/128)*NTB blocks of 256 threads; XCD swizzle.
// ---------------------------------------------------------------------------
template <typename CT, int NTB>
__global__ __launch_bounds__(256) void gemm_bt(
    const unsigned short* __restrict__ A,
    const unsigned short* __restrict__ Bt,
    const float* __restrict__ bias,
    CT* __restrict__ C,
    int K, int lda, int ldb, int ldc)
{
  __shared__ __align__(16) unsigned short sA[3][128 * 32];  // 24 KB
  __shared__ __align__(16) unsigned short sB[3][128 * 32];  // 24 KB

  const int tid = threadIdx.x;
  const int w   = tid >> 6;   // wave 0..3
  const int l   = tid & 63;
  const int l15 = l & 15;
  const int q   = l >> 4;     // quad 0..3

  // XCD-aware remap: dispatch -> (m,n) so one XCD owns all n-tiles of an m-row
  const int bt  = blockIdx.x;
  const int xcd = bt & 7;
  const int j_  = bt >> 3;
  const int n0  = (j_ % NTB) * 128;
  const int m0  = ((j_ / NTB) * 8 + xcd) * 128;

  const int wm  = (w >> 1) * 64;      // wave's 64x64 quadrant
  const int wn  = (w & 1) * 64;

  floatx4 acc[4][4];
  #pragma unroll
  for (int i = 0; i < 4; ++i)
    #pragma unroll
    for (int j = 0; j < 4; ++j)
      #pragma unroll
      for (int t = 0; t < 4; ++t) acc[i][j][t] = 0.f;

  // ---- staging geometry: per issue, wave covers 16 rows x 4 chunks (16B).
  // LDS dest is linear (lane*16B); global source pre-inverse-swizzled.
  const int sr  = l >> 2;                  // row within 16-row group
  const int pc_ = l & 3;                   // physical chunk
  const int lc  = pc_ ^ ((sr >> 1) & 3);   // logical chunk (inverse swizzle)
  const unsigned short* Asrc[2];
  const unsigned short* Bsrc[2];
  #pragma unroll
  for (int j = 0; j < 2; ++j) {
    const int rr = (w * 2 + j) * 16 + sr;
    Asrc[j] = A  + (size_t)(m0 + rr) * lda + lc * 8;
    Bsrc[j] = Bt + (size_t)(n0 + rr) * ldb + lc * 8;
  }

  // fragment read offsets (shorts): row*32 + swizzled-chunk*8
  const int fq   = (q ^ ((l15 >> 1) & 3)) * 8;
  const int aoff = (wm + l15) * 32 + fq;
  const int boff = (wn + l15) * 32 + fq;

  const int KT = K >> 5;   // K-tiles of 32

  // stage tile k0 into ring buffer b (4 async16 per wave)
  #define STAGE(k0, b)                                                   \
    {                                                                    \
      _Pragma("unroll")                                                  \
      for (int j = 0; j < 2; ++j) {                                      \
        async16(Asrc[j] + (k0), &sA[b][(w * 2 + j) * 512]);              \
        async16(Bsrc[j] + (k0), &sB[b][(w * 2 + j) * 512]);              \
      }                                                                  \
    }

  // ---- prologue: stage tiles 0 and 1; publish tile 0
  STAGE(0, 0);
  STAGE(32, 1);
  asm volatile("s_waitcnt vmcnt(4)" ::: "memory");  // tile 0 landed
  __builtin_amdgcn_s_barrier();

  int bc = 0;
  for (int t = 0; t < KT; ++t) {
    const int k2 = (t + 2) << 5;
    const int bs = (bc == 0) ? 2 : bc - 1;   // (bc+2)%3
    if (k2 < K) STAGE(k2, bs);               // issue loads FIRST (max flight)

    short8 af[4], bf[4];
    #pragma unroll
    for (int mt = 0; mt < 4; ++mt)
      af[mt] = *(const short8*)(&sA[bc][aoff + mt * 512]);
    #pragma unroll
    for (int nt = 0; nt < 4; ++nt)
      bf[nt] = *(const short8*)(&sB[bc][boff + nt * 512]);

    #pragma unroll
    for (int mt = 0; mt < 4; ++mt)
      #pragma unroll
      for (int nt = 0; nt < 4; ++nt)
        acc[mt][nt] = __builtin_amdgcn_mfma_f32_16x16x32_bf16(
            af[mt], bf[nt], acc[mt][nt], 0, 0, 0);

    if (k2 < K) {
      // drain tile t+1's 4 loads, keep tile t+2's 4 in flight
      asm volatile("s_waitcnt vmcnt(4)" ::: "memory");
    } else {
      asm volatile("s_waitcnt vmcnt(0)" ::: "memory");  // tail drain
    }
    if (t + 1 < KT) __builtin_amdgcn_s_barrier();
    bc = (bc == 2) ? 0 : bc + 1;
  }
  #undef STAGE

  // ---- epilogue: C/D layout col=lane&15, row=quad*4+reg
  #pragma unroll
  for (int nt = 0; nt < 4; ++nt) {
    const int col = n0 + wn + nt * 16 + l15;
    const float bs = bias[col];
    #pragma unroll
    for (int mt = 0; mt < 4; ++mt) {
      const int rbase = m0 + wm + mt * 16 + q * 4;
      #pragma unroll
      for (int r = 0; r < 4; ++r)
        storeC(C, (size_t)(rbase + r) * ldc + col, acc[mt][nt][r] + bs);
    }
  }
}

// 4 queries per wave, 16 lanes per query (lane p owns dims p*16..p*16+15).
// QKV row: [Q(0..255) | K(256..511) | V(512..767)], bf16. ctx overwrites Q
// slot in place (each group reads only its own Q row, before its store).
__global__ __launch_bounds__(256) void attn_win(unsigned short* QKV)
{
  const int l   = threadIdx.x & 63;
  const int grp = l >> 4;
  const int p   = l & 15;
  const int i   = blockIdx.x * 16 + (threadIdx.x >> 6) * 4 + grp;

  unsigned short* qrow = QKV + (size_t)i * 768 + p * 16;
  float qf[16];
  {
    const short8 v0 = *(const short8*)(qrow);
    const short8 v1 = *(const short8*)(qrow + 8);
    #pragma unroll
    for (int t = 0; t < 8; ++t) {
      qf[t]     = b2f((unsigned short)v0[t]);
      qf[8 + t] = b2f((unsigned short)v1[t]);
    }
  }

  float sc[9];
  #pragma unroll
  for (int wd = 0; wd < 9; ++wd) {
    const int j = i - 8 + wd;
    if (j >= 0) {
      const unsigned short* krow = QKV + (size_t)j * 768 + 256 + p * 16;
      const short8 v0 = *(const short8*)(krow);
      const short8 v1 = *(const short8*)(krow + 8);
      float d = 0.f;
      #pragma unroll
      for (int t = 0; t < 8; ++t) {
        d += qf[t]     * b2f((unsigned short)v0[t]);
        d += qf[8 + t] * b2f((unsigned short)v1[t]);
      }
      d += __shfl_xor(d, 8, 64);
      d += __shfl_xor(d, 4, 64);
      d += __shfl_xor(d, 2, 64);
      d += __shfl_xor(d, 1, 64);
      sc[wd] = d * 0.0625f;  // 1/sqrt(256)
    } else {
      sc[wd] = -1e30f;  // finite sentinel
    }
  }

  float mx = sc[0];
  #pragma unroll
  for (int wd = 1; wd < 9; ++wd) mx = fmaxf(mx, sc[wd]);
  float e[9], s = 0.f;
  #pragma unroll
  for (int wd = 0; wd < 9; ++wd) { e[wd] = __expf(sc[wd] - mx); s += e[wd]; }
  const float inv = 1.0f / s;

  float acc[16];
  #pragma unroll
  for (int t = 0; t < 16; ++t) acc[t] = 0.f;
  #pragma unroll
  for (int wd = 0; wd < 9; ++wd) {
    const int j = i - 8 + wd;
    if (j >= 0) {
      const unsigned short* vrow = QKV + (size_t)j * 768 + 512 + p * 16;
      const short8 v0 = *(const short8*)(vrow);
      const short8 v1 = *(const short8*)(vrow + 8);
      #pragma unroll
      for (int t = 0; t < 8; ++t) {
        acc[t]     += e[wd] * b2f((unsigned short)v0[t]);
        acc[8 + t] += e[wd] * b2f((unsigned short)v1[t]);
      }
    }
  }
  short8 o0, o1;
  #pragma unroll
  for (int t = 0; t < 8; ++t) {
    o0[t] = (short)f2b(acc[t] * inv);
    o1[t] = (short)f2b(acc[8 + t] * inv);
  }
  *(short8*)(qrow)     = o0;
  *(short8*)(qrow + 8) = o1;
}

// Coalesced weight transposes via 32x32 LDS tiles (f32 -> bf16) + biases.
__global__ __launch_bounds__(256) void prep_w(
    const float* __restrict__ Wq, const float* __restrict__ Wk,
    const float* __restrict__ Wv, const float* __restrict__ Wo,
    const float* __restrict__ bq, const float* __restrict__ bk,
    const float* __restrict__ bv, const float* __restrict__ bo,
    unsigned short* __restrict__ Wt,   // [768][1024] bf16
    unsigned short* __restrict__ Wot,  // [1024][256] bf16
    float* __restrict__ bias1,         // [768] f32
    float* __restrict__ bias2)         // [1024] f32
{
  const int tt = blockIdx.x;
  if (tt < 1024) {
    __shared__ float tile[32][33];
    const float* src; unsigned short* dst; int N, Kd, k0, n0;
    if (tt < 768) {
      const int s = tt >> 8;          // 0:Wq 1:Wk 2:Wv
      const int r = tt & 255;
      src = (s == 0) ? Wq : (s == 1) ? Wk : Wv;
      N = 256; Kd = 1024;
      k0 = (r & 31) * 32;
      n0 = (r >> 5) * 32;
      dst = Wt + (size_t)s * 256 * 1024;
    } else {
      const int r = tt - 768;
      src = Wo; N = 1024; Kd = 256;
      k0 = (r & 7) * 32;
      n0 = (r >> 3) * 32;
      dst = Wot;
    }
    const int t  = threadIdx.x;
    const int rr = t >> 3;
    const int c4 = (t & 7) * 4;
    const float4 v = *(const float4*)(src + (size_t)(k0 + rr) * N + n0 + c4);
    tile[rr][c4 + 0] = v.x; tile[rr][c4 + 1] = v.y;
    tile[rr][c4 + 2] = v.z; tile[rr][c4 + 3] = v.w;
    __syncthreads();
    ushort4 o;
    o.x = f2b(tile[c4 + 0][rr]); o.y = f2b(tile[c4 + 1][rr]);
    o.z = f2b(tile[c4 + 2][rr]); o.w = f2b(tile[c4 + 3][rr]);
    *(ushort4*)(dst + (size_t)(n0 + rr) * Kd + k0 + c4) = o;
  } else {
    for (int c = threadIdx.x; c < 1792; c += 256) {
      if (c < 768)
        bias1[c] = (c < 256) ? bq[c] : (c < 512) ? bk[c - 256] : bv[c - 512];
      else
        bias2[c - 768] = bo[c - 768];
    }
  }
}

extern "C" void kernel_launch(void* const* d_in, const int* in_sizes, int n_in,
                              void* d_out, int out_size, void* d_ws, size_t ws_size,
                              hipStream_t stream) {
  const float* x  = (const float*)d_in[0];
  const float* Wq = (const float*)d_in[1];
  const float* Wk = (const float*)d_in[2];
  const float* Wv = (const float*)d_in[3];
  const float* Wo = (const float*)d_in[4];
  const float* bq = (const float*)d_in[5];
  const float* bk = (const float*)d_in[6];
  const float* bv = (const float*)d_in[7];
  const float* bo = (const float*)d_in[8];
  float* out = (float*)d_out;

  // workspace layout — xb spills into d_out if ws is small
  // (d_out = 134 MB, only consumed by the last GEMM => stream-ordered safe).
  unsigned short* ws    = (unsigned short*)d_ws;
  unsigned short* Wt    = ws;                        //   786432 bf16
  unsigned short* Wot   = Wt  + 786432;              //   262144 bf16
  float*          bias1 = (float*)(Wot + 262144);    //      768 f32
  float*          bias2 = bias1 + 768;               //     1024 f32
  unsigned short* QKV   = (unsigned short*)(bias2 + 1024);  // 25165824 bf16
  unsigned short* xb;                                // 33554432 bf16
  const size_t need = 119544832;                     // bytes incl. xb
  if (ws_size >= need) xb = QKV + 25165824;
  else                 xb = (unsigned short*)d_out;  // scratch until last GEMM

  prep_w<<<1025, 256, 0, stream>>>(Wq, Wk, Wv, Wo, bq, bk, bv, bo,
                                   Wt, Wot, bias1, bias2);

  // x f32 -> bf16
  cvt_x<<<2048, 256, 0, stream>>>(x, xb, 32768 * 1024 / 8);

  // QKV = x @ [Wq|Wk|Wv] + bias   (M=32768, N=768, K=1024)
  gemm_bt<unsigned short, 6><<<1536, 256, 0, stream>>>(
      xb, Wt, bias1, QKV, 1024, 1024, 1024, 768);

  // windowed attention: ctx overwrites the Q slot of QKV
  attn_win<<<2048, 256, 0, stream>>>(QKV);

  // out = ctx @ Wo + bo   (M=32768, N=1024, K=256; A = QKV with lda=768)
  gemm_bt<float, 8><<<2048, 256, 0, stream>>>(
      QKV, Wot, bias2, out, 256, 768, 256, 1024);
}